// Round 13
// baseline (64.010 us; speedup 1.0000x reference)
//
#include <hip/hip_runtime.h>
#include <hip/hip_fp16.h>

typedef __attribute__((ext_vector_type(8))) _Float16 half8;
typedef __attribute__((ext_vector_type(4))) float f32x4;

union U2H2 { unsigned int u; __half2 h; };

static __device__ __forceinline__ unsigned int pack2h(float a, float b) {
    U2H2 c; c.h = __floats2half2_rn(a, b); return c.u;
}
static __device__ __forceinline__ __half2 u_as_h2(unsigned int u) {
    U2H2 c; c.u = u; return c.h;
}
static __device__ __forceinline__ __half2 hi16(unsigned int u) {
    return u_as_h2(__builtin_amdgcn_perm(u, u, 0x03020302u));
}

// swizzle: slot' = slot ^ (row&3) ^ ((row>>2)&3) — conflict-free for the
// 4-lane-per-row writes and 16-consecutive-row fragment reads
#define SWZ(row, slot) ((slot) ^ ((row) & 3) ^ (((row) >> 2) & 3))

// fence LDS + barrier WITHOUT draining vmcnt (prefetched loads stay in flight)
#define LDS_BARRIER()                                                \
    do {                                                             \
        asm volatile("s_waitcnt lgkmcnt(0)" ::: "memory");           \
        __builtin_amdgcn_s_barrier();                                \
        __builtin_amdgcn_sched_barrier(0);                           \
    } while (0)

// Prep: blocks [0,nT): transpose x -> xth [N][2][32] fp16 (b-halves share a
// 128B line); blocks [nT,nT+25): repack W -> Wrh[k][o][c] fp16.
__global__ __launch_bounds__(256) void prep_all(const float* __restrict__ x,
                                                const float* __restrict__ W,
                                                unsigned short* __restrict__ xth,
                                                unsigned short* __restrict__ Wrh,
                                                int N, int nT) {
    int bid = blockIdx.x, tid = threadIdx.x;
    if (bid >= nT) {
        int k = bid - nT;  // 0..24
#pragma unroll
        for (int it = 0; it < 8; ++it) {
            int r = tid + 256 * it;          // 0..2047 = o*32+c
            int o = r >> 5, c = r & 31;
            __half h = __float2half(W[o * 800 + c * 25 + k]);
            Wrh[k * 2048 + r] = *reinterpret_cast<unsigned short*>(&h);
        }
        return;
    }
    __shared__ float t[2][32][65];
    int n0 = bid * 64;
#pragma unroll
    for (int i = 0; i < 16; ++i) {
        int e = tid + 256 * i;               // [2][32][64]
        int b = e >> 11, c = (e >> 6) & 31, nl = e & 63;
        int n = n0 + nl;
        t[b][c][nl] = (n < N) ? x[(size_t)(b * 32 + c) * N + n] : 0.f;
    }
    __syncthreads();
    int nl = tid >> 2, q = tid & 3, n = n0 + nl;
    if (n < N) {
#pragma unroll
        for (int b = 0; b < 2; ++b) {
            uint4 p;
            p.x = pack2h(t[b][q * 8 + 0][nl], t[b][q * 8 + 1][nl]);
            p.y = pack2h(t[b][q * 8 + 2][nl], t[b][q * 8 + 3][nl]);
            p.z = pack2h(t[b][q * 8 + 4][nl], t[b][q * 8 + 5][nl]);
            p.w = pack2h(t[b][q * 8 + 6][nl], t[b][q * 8 + 7][nl]);
            *reinterpret_cast<uint4*>(xth + ((size_t)n * 64 + b * 32 + q * 8)) = p;
        }
    }
}

// Fused gather + einsum + MFMA + bias. 16-n tile, 128-thread blocks (2-wave
// barrier convoy), paired 128B-line gathers (8 lanes per (n,t)), idx reads
// scheduled AFTER the barrier so the pre-barrier drain covers only LDS writes.
__global__ __launch_bounds__(128) void fused_main(
    const unsigned short* __restrict__ xth,  // [N][2][32] fp16
    const unsigned short* __restrict__ Wrh,  // [25][64][32] fp16
    const float* __restrict__ bias,          // [64]
    const int* __restrict__ nidx,            // [N][25][3]
    const float* __restrict__ nw,            // [N][25][3]
    float* __restrict__ out,                 // [2][64][N] fp32
    int N)
{
    __shared__ unsigned int idxw[16 * 104];              // [nl][26][4]: j | half(w)<<16
    __shared__ __align__(16) unsigned char sA[2][2048];  // dbuf: 32 rows (2b x 16n) x 64B
    __shared__ __align__(16) unsigned char sB[2][4096];  // dbuf: 64 o-rows x 64B

    const int tid = threadIdx.x;
    const int n0 = blockIdx.x * 16;

    // ---- zero idx table, then fill slices 0..24 ----
#pragma unroll
    for (int it = 0; it < 13; ++it) {
        int e = tid + 128 * it;
        if (e < 1664) idxw[e] = 0u;
    }
    __syncthreads();
#pragma unroll
    for (int it = 0; it < 10; ++it) {
        int e = tid + 128 * it;
        if (e < 1200) {
            int nl = e / 75, r = e - nl * 75;
            int kk = r / 3, t = r - kk * 3;
            int n = n0 + nl;
            unsigned int u = 0;
            if (n < N) {
                size_t s = (size_t)n0 * 75 + e;
                int j = nidx[s];
                __half hw = __float2half(nw[s]);
                u = (unsigned int)j |
                    ((unsigned int)*reinterpret_cast<unsigned short*>(&hw) << 16);
            }
            idxw[nl * 104 + kk * 4 + t] = u;
        }
    }
    __syncthreads();

    const int nl = tid >> 3;                   // n-row 0..15 this thread gathers
    const int p8 = tid & 7;                    // 16B slice of the 128B pair-line
    const int grow = (p8 >> 2) * 16 + nl;      // sA row = b*16 + nl  (32 rows)
    const int gq = p8 & 3;                     // c-quad within the 64B half
    const int wr_off = grow * 64 + (SWZ(grow, gq) << 4);

    // sB staging: thread stages slots tid and tid+128 (o-row s>>2, quad s&3)
    const int s1 = tid + 128;
    const int sbo0 = (tid >> 2) * 64 + (SWZ((tid >> 2), (tid & 3)) << 4);
    const int sbo1 = (s1 >> 2) * 64 + (SWZ((s1 >> 2), (s1 & 3)) << 4);
    const int gbo0 = (tid >> 2) * 32 + (tid & 3) * 8;   // Wrh halfword offsets
    const int gbo1 = (s1 >> 2) * 32 + (s1 & 3) * 8;

    const int l = tid & 63, wv = tid >> 6, c16 = l & 15, g = l >> 4;
    const int arow = 16 * wv + c16;            // wave wv owns rows 16wv..16wv+15
    const int rd_a = arow * 64 + (SWZ(arow, g) << 4);

    const unsigned short* xg = xth + p8 * 8;   // + j*64 per gather
    const unsigned int* iprow = &idxw[nl * 104];

    unsigned int ru[3][3];
    uint4 rg[3][3];
    uint4 rB0, rB1;

    f32x4 acc[4];
#pragma unroll
    for (int ot = 0; ot < 4; ++ot) acc[ot] = (f32x4){0.f, 0.f, 0.f, 0.f};

    // ---- prologue: B(0); idx+gathers for slices 0..2 ----
    rB0 = *reinterpret_cast<const uint4*>(Wrh + gbo0);
    rB1 = *reinterpret_cast<const uint4*>(Wrh + gbo1);
#pragma unroll
    for (int kk = 0; kk < 3; ++kk) {
        uint4 iq = *reinterpret_cast<const uint4*>(iprow + kk * 4);
        ru[kk][0] = iq.x; ru[kk][1] = iq.y; ru[kk][2] = iq.z;
    }
#pragma unroll
    for (int kk = 0; kk < 3; ++kk)
#pragma unroll
        for (int t = 0; t < 3; ++t)
            rg[kk][t] = *reinterpret_cast<const uint4*>(xg + (ru[kk][t] & 0xffffu) * 64);

#pragma unroll
    for (int k = 0; k < 25; ++k) {
        const int gb = k % 3, buf = k & 1;

        // stage B slice; refill B(k+1) from global
        *reinterpret_cast<uint4*>(&sB[buf][sbo0]) = rB0;
        *reinterpret_cast<uint4*>(&sB[buf][sbo1]) = rB1;
        if (k + 1 < 25) {
            rB0 = *reinterpret_cast<const uint4*>(Wrh + (k + 1) * 2048 + gbo0);
            rB1 = *reinterpret_cast<const uint4*>(Wrh + (k + 1) * 2048 + gbo1);
        }

        // weighted fp16 sum of slice k's gathers -> sA[buf]
        {
            __half2 w0 = hi16(ru[gb][0]), w1 = hi16(ru[gb][1]), w2 = hi16(ru[gb][2]);
            uint4 v0 = rg[gb][0], v1 = rg[gb][1], v2 = rg[gb][2];
            uint4 pk; U2H2 c;
            c.h = __hfma2(u_as_h2(v0.x), w0, __hfma2(u_as_h2(v1.x), w1, __hmul2(u_as_h2(v2.x), w2)));
            pk.x = c.u;
            c.h = __hfma2(u_as_h2(v0.y), w0, __hfma2(u_as_h2(v1.y), w1, __hmul2(u_as_h2(v2.y), w2)));
            pk.y = c.u;
            c.h = __hfma2(u_as_h2(v0.z), w0, __hfma2(u_as_h2(v1.z), w1, __hmul2(u_as_h2(v2.z), w2)));
            pk.z = c.u;
            c.h = __hfma2(u_as_h2(v0.w), w0, __hfma2(u_as_h2(v1.w), w1, __hmul2(u_as_h2(v2.w), w2)));
            pk.w = c.u;
            *reinterpret_cast<uint4*>(&sA[buf][wr_off]) = pk;
        }

        // barrier drains ONLY the LDS writes above (idx reads come after)
        LDS_BARRIER();

        // idx read for slice k+3 (latency hidden under frag reads + MFMA)
        uint4 niq;
        {
            int ka = (k + 3 < 25) ? k + 3 : 24;
            niq = *reinterpret_cast<const uint4*>(iprow + ka * 4);
        }

        // MFMA: A wave-local rows, B shared slice
        {
            half8 af = *reinterpret_cast<const half8*>(&sA[buf][rd_a]);
#pragma unroll
            for (int ot = 0; ot < 4; ++ot) {
                int orow = ot * 16 + c16;
                half8 bf = *reinterpret_cast<const half8*>(
                    &sB[buf][orow * 64 + (SWZ(orow, g) << 4)]);
                acc[ot] = __builtin_amdgcn_mfma_f32_16x16x32_f16(af, bf, acc[ot], 0, 0, 0);
            }
        }

        // issue gathers for slice k+3 (stay in flight ~2.5 periods)
        if (k + 3 < 25) {
            ru[gb][0] = niq.x; ru[gb][1] = niq.y; ru[gb][2] = niq.z;
#pragma unroll
            for (int t = 0; t < 3; ++t)
                rg[gb][t] = *reinterpret_cast<const uint4*>(xg + (ru[gb][t] & 0xffffu) * 64);
        }
    }

    // ---- epilogue: bias + store (D: o = ot*16+c16, n-row = 4g+i, b = wv) ----
#pragma unroll
    for (int ot = 0; ot < 4; ++ot) {
        int o = ot * 16 + c16;
        float bv = bias[o];
#pragma unroll
        for (int i = 0; i < 4; ++i) {
            int n = n0 + 4 * g + i;
            if (n < N) out[((size_t)wv * 64 + o) * N + n] = acc[ot][i] + bv;
        }
    }
}

extern "C" void kernel_launch(void* const* d_in, const int* in_sizes, int n_in,
                              void* d_out, int out_size, void* d_ws, size_t ws_size,
                              hipStream_t stream) {
    const float* x    = (const float*)d_in[0];   // (2,32,N)
    const float* nw   = (const float*)d_in[1];   // (N,25,3)
    const float* W    = (const float*)d_in[2];   // (64,800)
    const float* bias = (const float*)d_in[3];   // (64,)
    const int*   nidx = (const int*)d_in[4];     // (N,25,3)
    float* out = (float*)d_out;

    int N = in_sizes[0] / 64;  // B*C = 64

    unsigned short* xth = (unsigned short*)d_ws;      // [N][2][32] fp16
    unsigned short* Wrh = xth + (size_t)N * 64;       // [25][64][32] fp16

    int nT = (N + 63) / 64;
    prep_all<<<nT + 25, 256, 0, stream>>>(x, W, xth, Wrh, N, nT);

    fused_main<<<(N + 15) / 16, 128, 0, stream>>>(xth, Wrh, bias, nidx, nw, out, N);
}